// Round 5
// baseline (322.568 us; speedup 1.0000x reference)
//
#include <hip/hip_runtime.h>

#define N_NODES 50000
#define N_EDGES 800000
#define D 128
#define N_LAYERS 3
#define OUT_F 16
#define N_GRAPHS 128
#define NBUCK 391            // ceil(50000/128) buckets of 128 nodes
#define EPB 4096             // edges per partition block
#define NB3 ((N_EDGES + EPB - 1) / EPB)  // 196
#define CAP 4096             // padded bucket capacity (mean 2048, sigma ~45)
#define NT32 ((N_NODES + 31) / 32)       // 1563 row-tiles of 32
#define PITCH 132            // LDS tile pitch in shorts (264B)
#define NCAST 6250           // cast blocks: 50000*128/4/256
#define NPREPW 96            // prep_w blocks: 24576/256
#define NHB 782              // half-buckets of 64 nodes

typedef __attribute__((ext_vector_type(8))) short short8;
typedef __attribute__((ext_vector_type(16))) float floatx16;

__device__ __forceinline__ unsigned short f2bf(float f) {
  unsigned int u = __float_as_uint(f);
  u += 0x7fff + ((u >> 16) & 1);   // RNE
  return (unsigned short)(u >> 16);
}
__device__ __forceinline__ float bf2f(unsigned short b) {
  return __uint_as_float(((unsigned int)b) << 16);
}
__device__ __forceinline__ float blo(unsigned v) { return __uint_as_float(v << 16); }
__device__ __forceinline__ float bhi(unsigned v) { return __uint_as_float(v & 0xffff0000u); }

// ========== CSR build: padded-bucket counting sort (2 kernels) ==============
__global__ __launch_bounds__(256) void partition_kernel(
    const int* __restrict__ src, const int* __restrict__ dst,
    int* __restrict__ cursor, unsigned* __restrict__ pairs) {
  __shared__ unsigned pk[EPB];
  __shared__ int hist[NBUCK];
  __shared__ int wcur[NBUCK];
  const int e0 = blockIdx.x * EPB;
  const int n = min(EPB, N_EDGES - e0);
  const int t = threadIdx.x;
  for (int i = t; i < NBUCK; i += 256) hist[i] = 0;
  __syncthreads();
  for (int i = t; i < n; i += 256) {
    int d = dst[e0 + i], s = src[e0 + i];
    pk[i] = ((unsigned)d << 16) | (unsigned)s;
    atomicAdd(&hist[d >> 7], 1);
  }
  __syncthreads();
  for (int i = t; i < NBUCK; i += 256)
    wcur[i] = i * CAP + (hist[i] ? atomicAdd(&cursor[i], hist[i]) : 0);
  __syncthreads();
  for (int i = t; i < n; i += 256) {
    unsigned p = pk[i];
    int pos = atomicAdd(&wcur[p >> 23], 1);
    pairs[pos] = p;
  }
}

__global__ __launch_bounds__(256) void bucket_sort_kernel(
    const unsigned* __restrict__ pairs, const int* __restrict__ cursor,
    int* __restrict__ rowbeg, int* __restrict__ rowend, int* __restrict__ esrc) {
  __shared__ unsigned pk[CAP];
  __shared__ int sorted[CAP];
  __shared__ int hist[128], off[128], cur[128];
  const int bkt = blockIdx.x;
  const int t = threadIdx.x;
  const int beg = bkt * CAP;
  const int cnt = cursor[bkt];
  if (t < 128) hist[t] = 0;
  __syncthreads();
  for (int i = t; i < cnt; i += 256) {
    unsigned p = pairs[beg + i];
    pk[i] = p;
    atomicAdd(&hist[(p >> 16) & 127], 1);
  }
  __syncthreads();
  if (t < 128) off[t] = hist[t];
  __syncthreads();
  for (int o = 1; o < 128; o <<= 1) {
    int x = (t < 128 && t >= o) ? off[t - o] : 0;
    __syncthreads();
    if (t < 128) off[t] += x;
    __syncthreads();
  }
  if (t < 128) {
    int node = bkt * 128 + t;
    if (node < N_NODES) {
      rowbeg[node] = beg + off[t] - hist[t];
      rowend[node] = beg + off[t];
    }
    cur[t] = off[t] - hist[t];
  }
  __syncthreads();
  for (int i = t; i < cnt; i += 256) {
    unsigned p = pk[i];
    int pos = atomicAdd(&cur[(p >> 16) & 127], 1);
    sorted[pos] = (int)(p & 0xFFFFu);
  }
  __syncthreads();
  for (int i = t; i < cnt; i += 256) esrc[beg + i] = sorted[i];
}

// ====== prep_all: cast x -> bf16, weights -> MFMA frags, zero cursor ========
// wt layout: [l][p:4][kst:32][lane:64][j:8] bf16 (p = phase = 32-col group).
// Element (lane,j) = B[kx][n], n = p*32+(lane&31), kx = kst*16+(lane>>5)*8+j;
// kx = seg*128+k, segs {rel_hi,rel_lo,root_hi,root_lo}.
__global__ __launch_bounds__(256) void prep_all_kernel(
    const float* __restrict__ x, unsigned short* __restrict__ x16,
    const float* __restrict__ Wrel, const float* __restrict__ Wroot,
    unsigned short* __restrict__ wt, int* __restrict__ cursor) {
  const int bid = blockIdx.x;
  const int t = threadIdx.x;
  if (bid < NCAST) {                       // ---- cast x (4 floats/thread) ----
    const int i = bid * 256 + t;
    const float4 v = *(const float4*)&x[(size_t)i * 4];
    uint2 o;
    o.x = f2bf(v.x) | ((unsigned)f2bf(v.y) << 16);
    o.y = f2bf(v.z) | ((unsigned)f2bf(v.w) << 16);
    *(uint2*)&x16[(size_t)i * 4] = o;
  } else if (bid < NCAST + NPREPW) {       // ---- weight fragments ----
    const int idx = (bid - NCAST) * 256 + t;
    const int lane = idx & 63;
    const int kst = (idx >> 6) & 31;
    const int nt = (idx >> 11) & 1;
    const int half = (idx >> 12) & 1;
    const int l = idx >> 13;
    const int n = half * 64 + nt * 32 + (lane & 31);
    const int kx0 = kst * 16 + (lane >> 5) * 8;
    const int seg = kx0 >> 7;              // same seg for all 8 j
    const int k0 = kx0 & 127;
    const int mat = seg >> 1, lo = seg & 1;
    const float* W = (mat ? Wroot : Wrel) + (size_t)l * D * D;
    unsigned short v[8];
#pragma unroll
    for (int j = 0; j < 8; ++j) {
      float w = W[(size_t)(k0 + j) * D + n];
      unsigned short hi = f2bf(w);
      v[j] = lo ? f2bf(w - bf2f(hi)) : hi;
    }
    unsigned short* dstp =
        wt + ((size_t)l * 128 + (half * 2 + nt) * 32 + kst) * 512 + lane * 8;
    *(uint4*)dstp = *(const uint4*)v;
  } else {                                 // ---- zero cursor ----
    const int i = (bid - NCAST - NPREPW) * 256 + t;
    if (i < NBUCK) cursor[i] = 0;
  }
}

// ========== agg: XCD-affine COLUMN-WINDOW gather (cache-line slices) ========
// h stays row-major; slice s = cols [s*32, s*32+32) = one 64B line per row.
// Work partition: xcd = bid & 7 (round-robin dispatch), slice = xcd >> 1 ->
// each XCD only touches 1/4 of h's lines = 3.2 MB -> L2-resident, 8x reuse.
// 64 groups x 4 lanes; group owns one node, 4 lanes read the 64B slice-row.
__global__ __launch_bounds__(256, 8) void agg_kernel(
    const unsigned short* __restrict__ h,
    const int* __restrict__ rowbeg, const int* __restrict__ rowend,
    const int* __restrict__ esrc, unsigned short* __restrict__ agg) {
  const int bid = blockIdx.x;              // 782*8 = 6256 blocks
  const int xcd = bid & 7;
  const int slice = xcd >> 1;              // XCD pair -> column window
  const int bh = (bid >> 3) * 2 + (xcd & 1);   // half-bucket 0..781
  const int t = threadIdx.x;
  const int g = t >> 2, li = t & 3;        // 64 groups x 4 lanes
  const int node = bh * 64 + g;
  if (node >= N_NODES) return;
  const unsigned short* hp = h + slice * 32 + li * 8;
  int e = rowbeg[node];
  const int end = rowend[node];
  float a0 = 0, a1 = 0, a2 = 0, a3 = 0, a4 = 0, a5 = 0, a6 = 0, a7 = 0;
  for (; e + 4 <= end; e += 4) {
    const int s0 = esrc[e],     s1 = esrc[e + 1];
    const int s2 = esrc[e + 2], s3 = esrc[e + 3];
    const uint4 v0 = *(const uint4*)&hp[(size_t)s0 * D];
    const uint4 v1 = *(const uint4*)&hp[(size_t)s1 * D];
    const uint4 v2 = *(const uint4*)&hp[(size_t)s2 * D];
    const uint4 v3 = *(const uint4*)&hp[(size_t)s3 * D];
    a0 += blo(v0.x) + blo(v1.x) + blo(v2.x) + blo(v3.x);
    a1 += bhi(v0.x) + bhi(v1.x) + bhi(v2.x) + bhi(v3.x);
    a2 += blo(v0.y) + blo(v1.y) + blo(v2.y) + blo(v3.y);
    a3 += bhi(v0.y) + bhi(v1.y) + bhi(v2.y) + bhi(v3.y);
    a4 += blo(v0.z) + blo(v1.z) + blo(v2.z) + blo(v3.z);
    a5 += bhi(v0.z) + bhi(v1.z) + bhi(v2.z) + bhi(v3.z);
    a6 += blo(v0.w) + blo(v1.w) + blo(v2.w) + blo(v3.w);
    a7 += bhi(v0.w) + bhi(v1.w) + bhi(v2.w) + bhi(v3.w);
  }
  for (; e < end; ++e) {
    const uint4 v0 = *(const uint4*)&hp[(size_t)esrc[e] * D];
    a0 += blo(v0.x); a1 += bhi(v0.x);
    a2 += blo(v0.y); a3 += bhi(v0.y);
    a4 += blo(v0.z); a5 += bhi(v0.z);
    a6 += blo(v0.w); a7 += bhi(v0.w);
  }
  uint4 o;
  o.x = f2bf(a0) | ((unsigned)f2bf(a1) << 16);
  o.y = f2bf(a2) | ((unsigned)f2bf(a3) << 16);
  o.z = f2bf(a4) | ((unsigned)f2bf(a5) << 16);
  o.w = f2bf(a6) | ((unsigned)f2bf(a7) << 16);
  *(uint4*)&agg[(size_t)node * D + slice * 32 + li * 8] = o;
}

// ========== GEMM: 8-wave block = 1 tile (32 rows), split chains =============
// Waves 0-3 = rel chain (agg x Wrel), waves 4-7 = root chain (h x Wroot);
// root waves deposit acc in LDS, rel waves sum + bias + relu + store.
__global__ __launch_bounds__(512, 8) void gemm_kernel(
    const unsigned short* __restrict__ agg, const unsigned short* __restrict__ hv,
    const unsigned short* __restrict__ wt,  // this layer's 128KB frag block
    const float* __restrict__ brel,
    unsigned short* __restrict__ outp) {
  __shared__ unsigned short atile[32 * PITCH];  // agg tile   (8.4 KB)
  __shared__ unsigned short htile[32 * PITCH];  // root tile  (8.4 KB)
  __shared__ float redB[4][16][64];             // root-chain acc (16 KB)
  const int t = threadIdx.x;
  const int r0 = blockIdx.x * 32;
  const int g = t >> 4, li = t & 15;            // 32 groups x 16 lanes
  const int row = r0 + g;
  if (row < N_NODES) {
    *(uint4*)&htile[g * PITCH + li * 8] =
        *(const uint4*)&hv[(size_t)row * D + li * 8];
    *(uint4*)&atile[g * PITCH + li * 8] =
        *(const uint4*)&agg[(size_t)row * D + li * 8];
  } else {
    const uint4 z = {0, 0, 0, 0};
    *(uint4*)&htile[g * PITCH + li * 8] = z;
    *(uint4*)&atile[g * PITCH + li * 8] = z;
  }
  __syncthreads();

  const int wave = t >> 6, lane = t & 63;
  const int p = wave & 3, chain = wave >> 2;    // chain 0=rel(agg), 1=root(h)
  const int r2 = lane & 31, hseg = lane >> 5;
  const unsigned short* tile = chain ? htile : atile;
  short8 fr[8];
#pragma unroll
  for (int i = 0; i < 8; ++i)
    fr[i] = *(const short8*)&tile[r2 * PITCH + i * 16 + hseg * 8];
  const unsigned short* ws = wt + (size_t)(p * 32 + chain * 16) * 512;
  floatx16 acc = {0.f};
#pragma unroll
  for (int k = 0; k < 16; ++k) {
    const short8 b = *(const short8*)&ws[(size_t)k * 512 + lane * 8];
    acc = __builtin_amdgcn_mfma_f32_32x32x16_bf16(fr[k & 7], b, acc, 0, 0, 0);
  }
  if (chain) {
#pragma unroll
    for (int reg = 0; reg < 16; ++reg) redB[p][reg][lane] = acc[reg];
  }
  __syncthreads();
  if (!chain) {
    const int cb = p * 32 + r2;
    const float bias = brel[cb];
#pragma unroll
    for (int reg = 0; reg < 16; ++reg) {
      const int orow = r0 + (reg & 3) + 8 * (reg >> 2) + 4 * hseg;
      if (orow < N_NODES)
        outp[(size_t)orow * D + cb] =
            f2bf(fmaxf(acc[reg] + redB[p][reg][lane] + bias, 0.f));
    }
  }
}

// ============= pool (segment ranges; batch sorted) + MLP head ===============
__device__ __forceinline__ int lb_search(const int* __restrict__ a, int n, int key) {
  int lo = 0, hi = n;
  while (lo < hi) {
    int m = (lo + hi) >> 1;
    if (a[m] < key) lo = m + 1; else hi = m;
  }
  return lo;
}

__global__ __launch_bounds__(256) void pool_head_kernel(
    const unsigned short* __restrict__ h, const int* __restrict__ batch,
    const float* __restrict__ W1, const float* __restrict__ b1,
    const float* __restrict__ W2, const float* __restrict__ b2,
    float* __restrict__ out) {
  __shared__ float sums_lds[16][128];
  __shared__ float pooled[128];
  __shared__ float hidden[128];
  __shared__ int range[2];
  const int g = blockIdx.x;
  const int t = threadIdx.x;
  if (t < 2) range[t] = lb_search(batch, N_NODES, g + t);
  __syncthreads();
  const int lo = range[0], hi = range[1];
  const int rg = t >> 4, cg = t & 15;
  float a0 = 0, a1 = 0, a2 = 0, a3 = 0, a4 = 0, a5 = 0, a6 = 0, a7 = 0;
  for (int n = lo + rg; n < hi; n += 16) {
    const uint4 v = *(const uint4*)&h[(size_t)n * D + cg * 8];
    a0 += blo(v.x); a1 += bhi(v.x);
    a2 += blo(v.y); a3 += bhi(v.y);
    a4 += blo(v.z); a5 += bhi(v.z);
    a6 += blo(v.w); a7 += bhi(v.w);
  }
  sums_lds[rg][cg * 8 + 0] = a0; sums_lds[rg][cg * 8 + 1] = a1;
  sums_lds[rg][cg * 8 + 2] = a2; sums_lds[rg][cg * 8 + 3] = a3;
  sums_lds[rg][cg * 8 + 4] = a4; sums_lds[rg][cg * 8 + 5] = a5;
  sums_lds[rg][cg * 8 + 6] = a6; sums_lds[rg][cg * 8 + 7] = a7;
  __syncthreads();
  if (t < 128) {
    float s = 0.f;
#pragma unroll
    for (int r = 0; r < 16; ++r) s += sums_lds[r][t];
    pooled[t] = s / fmaxf((float)(hi - lo), 1.f);
  }
  __syncthreads();
  if (t < 128) {
    float a = b1[t];
    for (int k = 0; k < D; ++k) a += pooled[k] * W1[k * D + t];
    hidden[t] = a;
  }
  __syncthreads();
  if (t < OUT_F) {
    float o = b2[t];
    for (int k = 0; k < D; ++k) o += hidden[k] * W2[k * OUT_F + t];
    out[(size_t)g * OUT_F + t] = o;
  }
}

// ============================== launch ======================================
extern "C" void kernel_launch(void* const* d_in, const int* in_sizes, int n_in,
                              void* d_out, int out_size, void* d_ws, size_t ws_size,
                              hipStream_t stream) {
  const float* x     = (const float*)d_in[0];
  const int*   ei    = (const int*)d_in[1];
  const int*   batch = (const int*)d_in[2];
  const float* Wrel  = (const float*)d_in[3];
  const float* brel  = (const float*)d_in[4];
  const float* Wroot = (const float*)d_in[5];
  const float* W1    = (const float*)d_in[6];
  const float* b1    = (const float*)d_in[7];
  const float* W2    = (const float*)d_in[8];
  const float* b2    = (const float*)d_in[9];
  float* out = (float*)d_out;

  const size_t ND = (size_t)N_NODES * D;
  unsigned short* bufA = (unsigned short*)d_ws;            // N*D bf16
  unsigned short* bufB = bufA + ND;                        // N*D bf16 (agg)
  unsigned short* bufC = bufB + ND;                        // N*D bf16 (x16)
  unsigned short* wt   = bufC + ND;                        // 3*128*512 bf16
  int* rowbeg = (int*)(wt + (size_t)N_LAYERS * 128 * 512); // N
  int* rowend = rowbeg + N_NODES;                          // N
  int* esrc   = rowend + N_NODES;                          // NBUCK*CAP
  unsigned* pairs = (unsigned*)(esrc + (size_t)NBUCK * CAP);  // NBUCK*CAP
  int* cursor = (int*)(pairs + (size_t)NBUCK * CAP);       // NBUCK

  const int* esrc_in = ei;
  const int* edst_in = ei + N_EDGES;

  // ---- prep (cast + weight frags + cursor zero) then CSR build ----
  prep_all_kernel<<<NCAST + NPREPW + 2, 256, 0, stream>>>(
      x, bufC, Wrel, Wroot, wt, cursor);
  partition_kernel<<<NB3, 256, 0, stream>>>(esrc_in, edst_in, cursor, pairs);
  bucket_sort_kernel<<<NBUCK, 256, 0, stream>>>(pairs, cursor, rowbeg, rowend, esrc);

  // ---- 3 layers: slice-affine agg + split-chain GEMM ----
  const size_t WL = (size_t)128 * 512;
  const int agg_blocks = NHB * 8;   // 6256; xcd = bid & 7
  // l0
  agg_kernel<<<agg_blocks, 256, 0, stream>>>(bufC, rowbeg, rowend, esrc, bufB);
  gemm_kernel<<<NT32, 512, 0, stream>>>(bufB, bufC, wt, brel, bufA);
  // l1
  agg_kernel<<<agg_blocks, 256, 0, stream>>>(bufA, rowbeg, rowend, esrc, bufB);
  gemm_kernel<<<NT32, 512, 0, stream>>>(bufB, bufA, wt + WL, brel + D, bufC);
  // l2
  agg_kernel<<<agg_blocks, 256, 0, stream>>>(bufC, rowbeg, rowend, esrc, bufB);
  gemm_kernel<<<NT32, 512, 0, stream>>>(bufB, bufC, wt + 2 * WL, brel + 2 * D, bufA);

  pool_head_kernel<<<N_GRAPHS, 256, 0, stream>>>(bufA, batch, W1, b1, W2, b2, out);
}

// Round 6
// 283.316 us; speedup vs baseline: 1.1385x; 1.1385x over previous
//
#include <hip/hip_runtime.h>

#define N_NODES 50000
#define N_EDGES 800000
#define D 128
#define N_LAYERS 3
#define OUT_F 16
#define N_GRAPHS 128
#define NBUCK 391            // ceil(50000/128) buckets of 128 nodes
#define EPB 4096             // edges per partition block
#define NB3 ((N_EDGES + EPB - 1) / EPB)  // 196
#define CAP 4096             // padded bucket capacity (mean 2048, sigma ~45)
#define NT32 ((N_NODES + 31) / 32)       // 1563 row-tiles of 32
#define PITCH 132            // LDS tile pitch in shorts (264B)
#define NCAST 6250           // cast blocks: 50000*128/4/256
#define NPREPW 96            // prep_w blocks: 24576/256

typedef __attribute__((ext_vector_type(8))) short short8;
typedef __attribute__((ext_vector_type(16))) float floatx16;

__device__ __forceinline__ unsigned short f2bf(float f) {
  unsigned int u = __float_as_uint(f);
  u += 0x7fff + ((u >> 16) & 1);   // RNE
  return (unsigned short)(u >> 16);
}
__device__ __forceinline__ float bf2f(unsigned short b) {
  return __uint_as_float(((unsigned int)b) << 16);
}
__device__ __forceinline__ float blo(unsigned v) { return __uint_as_float(v << 16); }
__device__ __forceinline__ float bhi(unsigned v) { return __uint_as_float(v & 0xffff0000u); }

// ========== CSR build: padded-bucket counting sort (2 kernels) ==============
__global__ __launch_bounds__(256) void partition_kernel(
    const int* __restrict__ src, const int* __restrict__ dst,
    int* __restrict__ cursor, unsigned* __restrict__ pairs) {
  __shared__ unsigned pk[EPB];
  __shared__ int hist[NBUCK];
  __shared__ int wcur[NBUCK];
  const int e0 = blockIdx.x * EPB;
  const int n = min(EPB, N_EDGES - e0);
  const int t = threadIdx.x;
  for (int i = t; i < NBUCK; i += 256) hist[i] = 0;
  __syncthreads();
  for (int i = t; i < n; i += 256) {
    int d = dst[e0 + i], s = src[e0 + i];
    pk[i] = ((unsigned)d << 16) | (unsigned)s;
    atomicAdd(&hist[d >> 7], 1);
  }
  __syncthreads();
  for (int i = t; i < NBUCK; i += 256)
    wcur[i] = i * CAP + (hist[i] ? atomicAdd(&cursor[i], hist[i]) : 0);
  __syncthreads();
  for (int i = t; i < n; i += 256) {
    unsigned p = pk[i];
    int pos = atomicAdd(&wcur[p >> 23], 1);
    pairs[pos] = p;
  }
}

__global__ __launch_bounds__(256) void bucket_sort_kernel(
    const unsigned* __restrict__ pairs, const int* __restrict__ cursor,
    int* __restrict__ rowbeg, int* __restrict__ rowend, int* __restrict__ esrc) {
  __shared__ unsigned pk[CAP];
  __shared__ int sorted[CAP];
  __shared__ int hist[128], off[128], cur[128];
  const int bkt = blockIdx.x;
  const int t = threadIdx.x;
  const int beg = bkt * CAP;
  const int cnt = cursor[bkt];
  if (t < 128) hist[t] = 0;
  __syncthreads();
  for (int i = t; i < cnt; i += 256) {
    unsigned p = pairs[beg + i];
    pk[i] = p;
    atomicAdd(&hist[(p >> 16) & 127], 1);
  }
  __syncthreads();
  if (t < 128) off[t] = hist[t];
  __syncthreads();
  for (int o = 1; o < 128; o <<= 1) {
    int x = (t < 128 && t >= o) ? off[t - o] : 0;
    __syncthreads();
    if (t < 128) off[t] += x;
    __syncthreads();
  }
  if (t < 128) {
    int node = bkt * 128 + t;
    if (node < N_NODES) {
      rowbeg[node] = beg + off[t] - hist[t];
      rowend[node] = beg + off[t];
    }
    cur[t] = off[t] - hist[t];
  }
  __syncthreads();
  for (int i = t; i < cnt; i += 256) {
    unsigned p = pk[i];
    int pos = atomicAdd(&cur[(p >> 16) & 127], 1);
    sorted[pos] = (int)(p & 0xFFFFu);
  }
  __syncthreads();
  for (int i = t; i < cnt; i += 256) esrc[beg + i] = sorted[i];
}

// ====== prep_all: cast x -> bf16, weights -> MFMA frags, zero cursor ========
// wt layout: [l][p:4][kst:32][lane:64][j:8] bf16 (p = phase = 32-col group).
// Element (lane,j) = B[kx][n], n = p*32+(lane&31), kx = kst*16+(lane>>5)*8+j;
// kx = seg*128+k, segs {rel_hi,rel_lo,root_hi,root_lo}.
__global__ __launch_bounds__(256) void prep_all_kernel(
    const float* __restrict__ x, unsigned short* __restrict__ x16,
    const float* __restrict__ Wrel, const float* __restrict__ Wroot,
    unsigned short* __restrict__ wt, int* __restrict__ cursor) {
  const int bid = blockIdx.x;
  const int t = threadIdx.x;
  if (bid < NCAST) {                       // ---- cast x (4 floats/thread) ----
    const int i = bid * 256 + t;
    const float4 v = *(const float4*)&x[(size_t)i * 4];
    uint2 o;
    o.x = f2bf(v.x) | ((unsigned)f2bf(v.y) << 16);
    o.y = f2bf(v.z) | ((unsigned)f2bf(v.w) << 16);
    *(uint2*)&x16[(size_t)i * 4] = o;
  } else if (bid < NCAST + NPREPW) {       // ---- weight fragments ----
    const int idx = (bid - NCAST) * 256 + t;
    const int lane = idx & 63;
    const int kst = (idx >> 6) & 31;
    const int nt = (idx >> 11) & 1;
    const int half = (idx >> 12) & 1;
    const int l = idx >> 13;
    const int n = half * 64 + nt * 32 + (lane & 31);
    const int kx0 = kst * 16 + (lane >> 5) * 8;
    const int seg = kx0 >> 7;              // same seg for all 8 j
    const int k0 = kx0 & 127;
    const int mat = seg >> 1, lo = seg & 1;
    const float* W = (mat ? Wroot : Wrel) + (size_t)l * D * D;
    unsigned short v[8];
#pragma unroll
    for (int j = 0; j < 8; ++j) {
      float w = W[(size_t)(k0 + j) * D + n];
      unsigned short hi = f2bf(w);
      v[j] = lo ? f2bf(w - bf2f(hi)) : hi;
    }
    unsigned short* dstp =
        wt + ((size_t)l * 128 + (half * 2 + nt) * 32 + kst) * 512 + lane * 8;
    *(uint4*)dstp = *(const uint4*)v;
  } else {                                 // ---- zero cursor ----
    const int i = (bid - NCAST - NPREPW) * 256 + t;
    if (i < NBUCK) cursor[i] = 0;
  }
}

// ===== aggregate: ROUND-0 geometry (measured ~18us standalone) ==============
// 16 lanes/node (4 nodes/wave), full 256B row per edge coalesced, 4-edge
// unroll, no barriers -> waves retire independently (no convoying).
__global__ __launch_bounds__(256) void agg_kernel(
    const unsigned short* __restrict__ h,
    const int* __restrict__ rowbeg, const int* __restrict__ rowend,
    const int* __restrict__ esrc, unsigned short* __restrict__ agg) {
  const int idx = blockIdx.x * 256 + threadIdx.x;
  const int n = idx >> 4;
  const int lane = idx & 15;
  if (n >= N_NODES) return;
  const int beg = rowbeg[n], end = rowend[n];
  float a0 = 0, a1 = 0, a2 = 0, a3 = 0, a4 = 0, a5 = 0, a6 = 0, a7 = 0;
  int e = beg;
  for (; e + 4 <= end; e += 4) {
    const int s0 = esrc[e],     s1 = esrc[e + 1];
    const int s2 = esrc[e + 2], s3 = esrc[e + 3];
    const uint4 v0 = *(const uint4*)&h[(size_t)s0 * D + lane * 8];
    const uint4 v1 = *(const uint4*)&h[(size_t)s1 * D + lane * 8];
    const uint4 v2 = *(const uint4*)&h[(size_t)s2 * D + lane * 8];
    const uint4 v3 = *(const uint4*)&h[(size_t)s3 * D + lane * 8];
    a0 += blo(v0.x) + blo(v1.x) + blo(v2.x) + blo(v3.x);
    a1 += bhi(v0.x) + bhi(v1.x) + bhi(v2.x) + bhi(v3.x);
    a2 += blo(v0.y) + blo(v1.y) + blo(v2.y) + blo(v3.y);
    a3 += bhi(v0.y) + bhi(v1.y) + bhi(v2.y) + bhi(v3.y);
    a4 += blo(v0.z) + blo(v1.z) + blo(v2.z) + blo(v3.z);
    a5 += bhi(v0.z) + bhi(v1.z) + bhi(v2.z) + bhi(v3.z);
    a6 += blo(v0.w) + blo(v1.w) + blo(v2.w) + blo(v3.w);
    a7 += bhi(v0.w) + bhi(v1.w) + bhi(v2.w) + bhi(v3.w);
  }
  for (; e < end; ++e) {
    const int s0 = esrc[e];
    const uint4 v0 = *(const uint4*)&h[(size_t)s0 * D + lane * 8];
    a0 += blo(v0.x); a1 += bhi(v0.x);
    a2 += blo(v0.y); a3 += bhi(v0.y);
    a4 += blo(v0.z); a5 += bhi(v0.z);
    a6 += blo(v0.w); a7 += bhi(v0.w);
  }
  uint4 o;
  o.x = f2bf(a0) | ((unsigned)f2bf(a1) << 16);
  o.y = f2bf(a2) | ((unsigned)f2bf(a3) << 16);
  o.z = f2bf(a4) | ((unsigned)f2bf(a5) << 16);
  o.w = f2bf(a6) | ((unsigned)f2bf(a7) << 16);
  *(uint4*)&agg[(size_t)n * D + lane * 8] = o;
}

// ========== GEMM: 8-wave block = 1 tile (32 rows), split chains =============
// Waves 0-3 = rel chain (agg x Wrel), waves 4-7 = root chain (h x Wroot);
// root waves deposit acc in LDS, rel waves sum + bias + relu + store.
// A read ONCE; B-frags streamed from L2-resident wt (128KB, replicated/XCD).
__global__ __launch_bounds__(512, 8) void gemm_kernel(
    const unsigned short* __restrict__ agg, const unsigned short* __restrict__ hv,
    const unsigned short* __restrict__ wt,  // this layer's 128KB frag block
    const float* __restrict__ brel,
    unsigned short* __restrict__ outp) {
  __shared__ unsigned short atile[32 * PITCH];  // agg tile   (8.4 KB)
  __shared__ unsigned short htile[32 * PITCH];  // root tile  (8.4 KB)
  __shared__ float redB[4][16][64];             // root-chain acc (16 KB)
  const int t = threadIdx.x;
  const int r0 = blockIdx.x * 32;
  const int g = t >> 4, li = t & 15;            // 32 groups x 16 lanes
  const int row = r0 + g;
  if (row < N_NODES) {
    *(uint4*)&htile[g * PITCH + li * 8] =
        *(const uint4*)&hv[(size_t)row * D + li * 8];
    *(uint4*)&atile[g * PITCH + li * 8] =
        *(const uint4*)&agg[(size_t)row * D + li * 8];
  } else {
    const uint4 z = {0, 0, 0, 0};
    *(uint4*)&htile[g * PITCH + li * 8] = z;
    *(uint4*)&atile[g * PITCH + li * 8] = z;
  }
  __syncthreads();

  const int wave = t >> 6, lane = t & 63;
  const int p = wave & 3, chain = wave >> 2;    // chain 0=rel(agg), 1=root(h)
  const int r2 = lane & 31, hseg = lane >> 5;
  const unsigned short* tile = chain ? htile : atile;
  short8 fr[8];
#pragma unroll
  for (int i = 0; i < 8; ++i)
    fr[i] = *(const short8*)&tile[r2 * PITCH + i * 16 + hseg * 8];
  const unsigned short* ws = wt + (size_t)(p * 32 + chain * 16) * 512;
  floatx16 acc = {0.f};
#pragma unroll
  for (int k = 0; k < 16; ++k) {
    const short8 b = *(const short8*)&ws[(size_t)k * 512 + lane * 8];
    acc = __builtin_amdgcn_mfma_f32_32x32x16_bf16(fr[k & 7], b, acc, 0, 0, 0);
  }
  if (chain) {
#pragma unroll
    for (int reg = 0; reg < 16; ++reg) redB[p][reg][lane] = acc[reg];
  }
  __syncthreads();
  if (!chain) {
    const int cb = p * 32 + r2;
    const float bias = brel[cb];
#pragma unroll
    for (int reg = 0; reg < 16; ++reg) {
      const int orow = r0 + (reg & 3) + 8 * (reg >> 2) + 4 * hseg;
      if (orow < N_NODES)
        outp[(size_t)orow * D + cb] =
            f2bf(fmaxf(acc[reg] + redB[p][reg][lane] + bias, 0.f));
    }
  }
}

// ============= pool (segment ranges; batch sorted) + MLP head ===============
__device__ __forceinline__ int lb_search(const int* __restrict__ a, int n, int key) {
  int lo = 0, hi = n;
  while (lo < hi) {
    int m = (lo + hi) >> 1;
    if (a[m] < key) lo = m + 1; else hi = m;
  }
  return lo;
}

__global__ __launch_bounds__(256) void pool_head_kernel(
    const unsigned short* __restrict__ h, const int* __restrict__ batch,
    const float* __restrict__ W1, const float* __restrict__ b1,
    const float* __restrict__ W2, const float* __restrict__ b2,
    float* __restrict__ out) {
  __shared__ float sums_lds[16][128];
  __shared__ float pooled[128];
  __shared__ float hidden[128];
  __shared__ int range[2];
  const int g = blockIdx.x;
  const int t = threadIdx.x;
  if (t < 2) range[t] = lb_search(batch, N_NODES, g + t);
  __syncthreads();
  const int lo = range[0], hi = range[1];
  const int rg = t >> 4, cg = t & 15;
  float a0 = 0, a1 = 0, a2 = 0, a3 = 0, a4 = 0, a5 = 0, a6 = 0, a7 = 0;
  for (int n = lo + rg; n < hi; n += 16) {
    const uint4 v = *(const uint4*)&h[(size_t)n * D + cg * 8];
    a0 += blo(v.x); a1 += bhi(v.x);
    a2 += blo(v.y); a3 += bhi(v.y);
    a4 += blo(v.z); a5 += bhi(v.z);
    a6 += blo(v.w); a7 += bhi(v.w);
  }
  sums_lds[rg][cg * 8 + 0] = a0; sums_lds[rg][cg * 8 + 1] = a1;
  sums_lds[rg][cg * 8 + 2] = a2; sums_lds[rg][cg * 8 + 3] = a3;
  sums_lds[rg][cg * 8 + 4] = a4; sums_lds[rg][cg * 8 + 5] = a5;
  sums_lds[rg][cg * 8 + 6] = a6; sums_lds[rg][cg * 8 + 7] = a7;
  __syncthreads();
  if (t < 128) {
    float s = 0.f;
#pragma unroll
    for (int r = 0; r < 16; ++r) s += sums_lds[r][t];
    pooled[t] = s / fmaxf((float)(hi - lo), 1.f);
  }
  __syncthreads();
  if (t < 128) {
    float a = b1[t];
    for (int k = 0; k < D; ++k) a += pooled[k] * W1[k * D + t];
    hidden[t] = a;
  }
  __syncthreads();
  if (t < OUT_F) {
    float o = b2[t];
    for (int k = 0; k < D; ++k) o += hidden[k] * W2[k * OUT_F + t];
    out[(size_t)g * OUT_F + t] = o;
  }
}

// ============================== launch ======================================
extern "C" void kernel_launch(void* const* d_in, const int* in_sizes, int n_in,
                              void* d_out, int out_size, void* d_ws, size_t ws_size,
                              hipStream_t stream) {
  const float* x     = (const float*)d_in[0];
  const int*   ei    = (const int*)d_in[1];
  const int*   batch = (const int*)d_in[2];
  const float* Wrel  = (const float*)d_in[3];
  const float* brel  = (const float*)d_in[4];
  const float* Wroot = (const float*)d_in[5];
  const float* W1    = (const float*)d_in[6];
  const float* b1    = (const float*)d_in[7];
  const float* W2    = (const float*)d_in[8];
  const float* b2    = (const float*)d_in[9];
  float* out = (float*)d_out;

  const size_t ND = (size_t)N_NODES * D;
  unsigned short* bufA = (unsigned short*)d_ws;            // N*D bf16
  unsigned short* bufB = bufA + ND;                        // N*D bf16 (agg)
  unsigned short* bufC = bufB + ND;                        // N*D bf16 (x16)
  unsigned short* wt   = bufC + ND;                        // 3*128*512 bf16
  int* rowbeg = (int*)(wt + (size_t)N_LAYERS * 128 * 512); // N
  int* rowend = rowbeg + N_NODES;                          // N
  int* esrc   = rowend + N_NODES;                          // NBUCK*CAP
  unsigned* pairs = (unsigned*)(esrc + (size_t)NBUCK * CAP);  // NBUCK*CAP
  int* cursor = (int*)(pairs + (size_t)NBUCK * CAP);       // NBUCK

  const int* esrc_in = ei;
  const int* edst_in = ei + N_EDGES;

  // ---- prep (cast + weight frags + cursor zero) then CSR build ----
  prep_all_kernel<<<NCAST + NPREPW + 2, 256, 0, stream>>>(
      x, bufC, Wrel, Wroot, wt, cursor);
  partition_kernel<<<NB3, 256, 0, stream>>>(esrc_in, edst_in, cursor, pairs);
  bucket_sort_kernel<<<NBUCK, 256, 0, stream>>>(pairs, cursor, rowbeg, rowend, esrc);

  // ---- 3 layers: standalone agg (round-0 geometry) + split-chain GEMM ----
  const size_t WL = (size_t)128 * 512;
  const int agg_blocks = (N_NODES * 16 + 255) / 256;   // 3125
  // l0
  agg_kernel<<<agg_blocks, 256, 0, stream>>>(bufC, rowbeg, rowend, esrc, bufB);
  gemm_kernel<<<NT32, 512, 0, stream>>>(bufB, bufC, wt, brel, bufA);
  // l1
  agg_kernel<<<agg_blocks, 256, 0, stream>>>(bufA, rowbeg, rowend, esrc, bufB);
  gemm_kernel<<<NT32, 512, 0, stream>>>(bufB, bufA, wt + WL, brel + D, bufC);
  // l2
  agg_kernel<<<agg_blocks, 256, 0, stream>>>(bufC, rowbeg, rowend, esrc, bufB);
  gemm_kernel<<<NT32, 512, 0, stream>>>(bufB, bufC, wt + 2 * WL, brel + 2 * D, bufA);

  pool_head_kernel<<<N_GRAPHS, 256, 0, stream>>>(bufA, batch, W1, b1, W2, b2, out);
}

// Round 7
// 277.300 us; speedup vs baseline: 1.1632x; 1.0217x over previous
//
#include <hip/hip_runtime.h>

#define N_NODES 50000
#define N_EDGES 800000
#define D 128
#define N_LAYERS 3
#define OUT_F 16
#define N_GRAPHS 128
#define NBUCK 391            // ceil(50000/128) buckets of 128 nodes
#define EPB 4096             // edges per partition block
#define NB3 ((N_EDGES + EPB - 1) / EPB)  // 196
#define CAP 4096             // padded bucket capacity (mean 2048, sigma ~45)
#define NT32 ((N_NODES + 31) / 32)       // 1563 row-tiles of 32
#define NGB ((NT32 + 7) / 8)             // 196 gemm blocks (8 tiles each)
#define PITCH 132            // LDS tile pitch in shorts (264B)
#define NCAST 6250           // cast blocks: 50000*128/4/256
#define NPREPW 96            // prep_w blocks: 24576/256

typedef __attribute__((ext_vector_type(8))) short short8;
typedef __attribute__((ext_vector_type(16))) float floatx16;

__device__ __forceinline__ unsigned short f2bf(float f) {
  unsigned int u = __float_as_uint(f);
  u += 0x7fff + ((u >> 16) & 1);   // RNE
  return (unsigned short)(u >> 16);
}
__device__ __forceinline__ float bf2f(unsigned short b) {
  return __uint_as_float(((unsigned int)b) << 16);
}
__device__ __forceinline__ float blo(unsigned v) { return __uint_as_float(v << 16); }
__device__ __forceinline__ float bhi(unsigned v) { return __uint_as_float(v & 0xffff0000u); }

// ========== CSR build: padded-bucket counting sort (2 kernels) ==============
__global__ __launch_bounds__(256) void partition_kernel(
    const int* __restrict__ src, const int* __restrict__ dst,
    int* __restrict__ cursor, unsigned* __restrict__ pairs) {
  __shared__ unsigned pk[EPB];
  __shared__ int hist[NBUCK];
  __shared__ int wcur[NBUCK];
  const int e0 = blockIdx.x * EPB;
  const int n = min(EPB, N_EDGES - e0);
  const int t = threadIdx.x;
  for (int i = t; i < NBUCK; i += 256) hist[i] = 0;
  __syncthreads();
  for (int i = t; i < n; i += 256) {
    int d = dst[e0 + i], s = src[e0 + i];
    pk[i] = ((unsigned)d << 16) | (unsigned)s;
    atomicAdd(&hist[d >> 7], 1);
  }
  __syncthreads();
  for (int i = t; i < NBUCK; i += 256)
    wcur[i] = i * CAP + (hist[i] ? atomicAdd(&cursor[i], hist[i]) : 0);
  __syncthreads();
  for (int i = t; i < n; i += 256) {
    unsigned p = pk[i];
    int pos = atomicAdd(&wcur[p >> 23], 1);
    pairs[pos] = p;
  }
}

__global__ __launch_bounds__(256) void bucket_sort_kernel(
    const unsigned* __restrict__ pairs, const int* __restrict__ cursor,
    int* __restrict__ rowbeg, int* __restrict__ rowend, int* __restrict__ esrc) {
  __shared__ unsigned pk[CAP];
  __shared__ int sorted[CAP];
  __shared__ int hist[128], off[128], cur[128];
  const int bkt = blockIdx.x;
  const int t = threadIdx.x;
  const int beg = bkt * CAP;
  const int cnt = cursor[bkt];
  if (t < 128) hist[t] = 0;
  __syncthreads();
  for (int i = t; i < cnt; i += 256) {
    unsigned p = pairs[beg + i];
    pk[i] = p;
    atomicAdd(&hist[(p >> 16) & 127], 1);
  }
  __syncthreads();
  if (t < 128) off[t] = hist[t];
  __syncthreads();
  for (int o = 1; o < 128; o <<= 1) {
    int x = (t < 128 && t >= o) ? off[t - o] : 0;
    __syncthreads();
    if (t < 128) off[t] += x;
    __syncthreads();
  }
  if (t < 128) {
    int node = bkt * 128 + t;
    if (node < N_NODES) {
      rowbeg[node] = beg + off[t] - hist[t];
      rowend[node] = beg + off[t];
    }
    cur[t] = off[t] - hist[t];
  }
  __syncthreads();
  for (int i = t; i < cnt; i += 256) {
    unsigned p = pk[i];
    int pos = atomicAdd(&cur[(p >> 16) & 127], 1);
    sorted[pos] = (int)(p & 0xFFFFu);
  }
  __syncthreads();
  for (int i = t; i < cnt; i += 256) esrc[beg + i] = sorted[i];
}

// ====== prep_all: cast x -> bf16, weights -> MFMA frags, zero cursor ========
// wt layout: [l][p:4][kst:32][lane:64][j:8] bf16 (p = phase = 32-col group).
// Element (lane,j) = B[kx][n], n = p*32+(lane&31), kx = kst*16+(lane>>5)*8+j;
// kx = seg*128+k, segs {rel_hi,rel_lo,root_hi,root_lo}.
__global__ __launch_bounds__(256) void prep_all_kernel(
    const float* __restrict__ x, unsigned short* __restrict__ x16,
    const float* __restrict__ Wrel, const float* __restrict__ Wroot,
    unsigned short* __restrict__ wt, int* __restrict__ cursor) {
  const int bid = blockIdx.x;
  const int t = threadIdx.x;
  if (bid < NCAST) {                       // ---- cast x (4 floats/thread) ----
    const int i = bid * 256 + t;
    const float4 v = *(const float4*)&x[(size_t)i * 4];
    uint2 o;
    o.x = f2bf(v.x) | ((unsigned)f2bf(v.y) << 16);
    o.y = f2bf(v.z) | ((unsigned)f2bf(v.w) << 16);
    *(uint2*)&x16[(size_t)i * 4] = o;
  } else if (bid < NCAST + NPREPW) {       // ---- weight fragments ----
    const int idx = (bid - NCAST) * 256 + t;
    const int lane = idx & 63;
    const int kst = (idx >> 6) & 31;
    const int nt = (idx >> 11) & 1;
    const int half = (idx >> 12) & 1;
    const int l = idx >> 13;
    const int n = half * 64 + nt * 32 + (lane & 31);
    const int kx0 = kst * 16 + (lane >> 5) * 8;
    const int seg = kx0 >> 7;              // same seg for all 8 j
    const int k0 = kx0 & 127;
    const int mat = seg >> 1, lo = seg & 1;
    const float* W = (mat ? Wroot : Wrel) + (size_t)l * D * D;
    unsigned short v[8];
#pragma unroll
    for (int j = 0; j < 8; ++j) {
      float w = W[(size_t)(k0 + j) * D + n];
      unsigned short hi = f2bf(w);
      v[j] = lo ? f2bf(w - bf2f(hi)) : hi;
    }
    unsigned short* dstp =
        wt + ((size_t)l * 128 + (half * 2 + nt) * 32 + kst) * 512 + lane * 8;
    *(uint4*)dstp = *(const uint4*)v;
  } else {                                 // ---- zero cursor ----
    const int i = (bid - NCAST - NPREPW) * 256 + t;
    if (i < NBUCK) cursor[i] = 0;
  }
}

// ===== aggregate: ROUND-0 geometry (measured ~18us standalone) ==============
// 16 lanes/node (4 nodes/wave), full 256B row per edge coalesced, 4-edge
// unroll, no barriers -> waves retire independently (no convoying).
__global__ __launch_bounds__(256) void agg_kernel(
    const unsigned short* __restrict__ h,
    const int* __restrict__ rowbeg, const int* __restrict__ rowend,
    const int* __restrict__ esrc, unsigned short* __restrict__ agg) {
  const int idx = blockIdx.x * 256 + threadIdx.x;
  const int n = idx >> 4;
  const int lane = idx & 15;
  if (n >= N_NODES) return;
  const int beg = rowbeg[n], end = rowend[n];
  float a0 = 0, a1 = 0, a2 = 0, a3 = 0, a4 = 0, a5 = 0, a6 = 0, a7 = 0;
  int e = beg;
  for (; e + 4 <= end; e += 4) {
    const int s0 = esrc[e],     s1 = esrc[e + 1];
    const int s2 = esrc[e + 2], s3 = esrc[e + 3];
    const uint4 v0 = *(const uint4*)&h[(size_t)s0 * D + lane * 8];
    const uint4 v1 = *(const uint4*)&h[(size_t)s1 * D + lane * 8];
    const uint4 v2 = *(const uint4*)&h[(size_t)s2 * D + lane * 8];
    const uint4 v3 = *(const uint4*)&h[(size_t)s3 * D + lane * 8];
    a0 += blo(v0.x) + blo(v1.x) + blo(v2.x) + blo(v3.x);
    a1 += bhi(v0.x) + bhi(v1.x) + bhi(v2.x) + bhi(v3.x);
    a2 += blo(v0.y) + blo(v1.y) + blo(v2.y) + blo(v3.y);
    a3 += bhi(v0.y) + bhi(v1.y) + bhi(v2.y) + bhi(v3.y);
    a4 += blo(v0.z) + blo(v1.z) + blo(v2.z) + blo(v3.z);
    a5 += bhi(v0.z) + bhi(v1.z) + bhi(v2.z) + bhi(v3.z);
    a6 += blo(v0.w) + blo(v1.w) + blo(v2.w) + blo(v3.w);
    a7 += bhi(v0.w) + bhi(v1.w) + bhi(v2.w) + bhi(v3.w);
  }
  for (; e < end; ++e) {
    const int s0 = esrc[e];
    const uint4 v0 = *(const uint4*)&h[(size_t)s0 * D + lane * 8];
    a0 += blo(v0.x); a1 += bhi(v0.x);
    a2 += blo(v0.y); a3 += bhi(v0.y);
    a4 += blo(v0.z); a5 += bhi(v0.z);
    a6 += blo(v0.w); a7 += bhi(v0.w);
  }
  uint4 o;
  o.x = f2bf(a0) | ((unsigned)f2bf(a1) << 16);
  o.y = f2bf(a2) | ((unsigned)f2bf(a3) << 16);
  o.z = f2bf(a4) | ((unsigned)f2bf(a5) << 16);
  o.w = f2bf(a6) | ((unsigned)f2bf(a7) << 16);
  *(uint4*)&agg[(size_t)n * D + lane * 8] = o;
}

// ========== GEMM: 8 tiles/block, B staged ONCE per block (fabric fix) =======
// 512 threads; wave w owns tile bid*8+w with A/h frags in REGISTERS (staged
// via 33KB LDS scratch, exact-traffic). Then B staged in two 64KB halves
// (phases 0-1, 2-3) consumed by all 8 waves -> wt traffic = 196x128KB = 25MB
// per layer (vs 200MB streamed). Each wave: 32 MFMAs/phase (rel then root
// ksteps into ONE acc, round-2 summation order), epilogue per phase.
__global__ __launch_bounds__(512, 2) void gemm_kernel(
    const unsigned short* __restrict__ agg, const unsigned short* __restrict__ hv,
    const unsigned short* __restrict__ wt,  // this layer's 128KB frag block
    const float* __restrict__ brel,
    unsigned short* __restrict__ outp) {
  __shared__ unsigned short lds[32768];         // 64 KB (scratch then B)
  const int t = threadIdx.x;
  const int wave = t >> 6, lane = t & 63;
  const int g = t >> 4, li = t & 15;            // 32 rows x 16 lanes staging
  const int r2 = lane & 31, hseg = lane >> 5;
  const int tile = blockIdx.x * 8 + wave;

  // ---- stage A/h frags: 4 rounds x 2 tiles through 33KB scratch ----
  short8 ag[8], hh[8];
#pragma unroll
  for (int r = 0; r < 4; ++r) {
#pragma unroll
    for (int j = 0; j < 4; ++j) {               // j = tile(0/1)*2 + which(a/h)
      int srow = (blockIdx.x * 8 + 2 * r + (j >> 1)) * 32 + g;
      if (srow >= N_NODES) srow = N_NODES - 1;
      const unsigned short* sp = (j & 1) ? hv : agg;
      *(uint4*)&lds[(j * 32 + g) * PITCH + li * 8] =
          *(const uint4*)&sp[(size_t)srow * D + li * 8];
    }
    __syncthreads();
    if ((wave >> 1) == r) {
      const int slot = wave & 1;
#pragma unroll
      for (int i = 0; i < 8; ++i) {
        ag[i] = *(const short8*)&lds[(slot * 2 + 0) * 32 * PITCH +
                                     r2 * PITCH + i * 16 + hseg * 8];
        hh[i] = *(const short8*)&lds[(slot * 2 + 1) * 32 * PITCH +
                                     r2 * PITCH + i * 16 + hseg * 8];
      }
    }
    __syncthreads();
  }

  const int r0 = tile * 32;
  // ---- 2 B-halves x 2 phases; B LDS-resident, shared by all 8 waves ----
#pragma unroll
  for (int pp = 0; pp < 2; ++pp) {
    const unsigned short* ws = wt + (size_t)pp * 32768;   // 64KB half
#pragma unroll
    for (int j = 0; j < 8; ++j) {
      const int idx = t + j * 512;              // 4096 uint4 units = 64KB
      *(uint4*)&lds[idx * 8] = *(const uint4*)&ws[idx * 8];
    }
    __syncthreads();
#pragma unroll
    for (int p2 = 0; p2 < 2; ++p2) {
      floatx16 acc = {0.f};
#pragma unroll
      for (int kst = 0; kst < 32; ++kst) {
        const short8 af = (kst < 16) ? ag[kst & 7] : hh[kst & 7];
        const short8 b = *(const short8*)&lds[(p2 * 32 + kst) * 512 + lane * 8];
        acc = __builtin_amdgcn_mfma_f32_32x32x16_bf16(af, b, acc, 0, 0, 0);
      }
      const int cb = (pp * 2 + p2) * 32 + r2;
      const float bias = brel[cb];
#pragma unroll
      for (int reg = 0; reg < 16; ++reg) {
        const int orow = r0 + (reg & 3) + 8 * (reg >> 2) + 4 * hseg;
        if (orow < N_NODES)
          outp[(size_t)orow * D + cb] = f2bf(fmaxf(acc[reg] + bias, 0.f));
      }
    }
    __syncthreads();                            // before overwriting B
  }
}

// ============= pool (segment ranges; batch sorted) + MLP head ===============
__device__ __forceinline__ int lb_search(const int* __restrict__ a, int n, int key) {
  int lo = 0, hi = n;
  while (lo < hi) {
    int m = (lo + hi) >> 1;
    if (a[m] < key) lo = m + 1; else hi = m;
  }
  return lo;
}

__global__ __launch_bounds__(256) void pool_head_kernel(
    const unsigned short* __restrict__ h, const int* __restrict__ batch,
    const float* __restrict__ W1, const float* __restrict__ b1,
    const float* __restrict__ W2, const float* __restrict__ b2,
    float* __restrict__ out) {
  __shared__ float sums_lds[16][128];
  __shared__ float pooled[128];
  __shared__ float hidden[128];
  __shared__ int range[2];
  const int g = blockIdx.x;
  const int t = threadIdx.x;
  if (t < 2) range[t] = lb_search(batch, N_NODES, g + t);
  __syncthreads();
  const int lo = range[0], hi = range[1];
  const int rg = t >> 4, cg = t & 15;
  float a0 = 0, a1 = 0, a2 = 0, a3 = 0, a4 = 0, a5 = 0, a6 = 0, a7 = 0;
  for (int n = lo + rg; n < hi; n += 16) {
    const uint4 v = *(const uint4*)&h[(size_t)n * D + cg * 8];
    a0 += blo(v.x); a1 += bhi(v.x);
    a2 += blo(v.y); a3 += bhi(v.y);
    a4 += blo(v.z); a5 += bhi(v.z);
    a6 += blo(v.w); a7 += bhi(v.w);
  }
  sums_lds[rg][cg * 8 + 0] = a0; sums_lds[rg][cg * 8 + 1] = a1;
  sums_lds[rg][cg * 8 + 2] = a2; sums_lds[rg][cg * 8 + 3] = a3;
  sums_lds[rg][cg * 8 + 4] = a4; sums_lds[rg][cg * 8 + 5] = a5;
  sums_lds[rg][cg * 8 + 6] = a6; sums_lds[rg][cg * 8 + 7] = a7;
  __syncthreads();
  if (t < 128) {
    float s = 0.f;
#pragma unroll
    for (int r = 0; r < 16; ++r) s += sums_lds[r][t];
    pooled[t] = s / fmaxf((float)(hi - lo), 1.f);
  }
  __syncthreads();
  if (t < 128) {
    float a = b1[t];
    for (int k = 0; k < D; ++k) a += pooled[k] * W1[k * D + t];
    hidden[t] = a;
  }
  __syncthreads();
  if (t < OUT_F) {
    float o = b2[t];
    for (int k = 0; k < D; ++k) o += hidden[k] * W2[k * OUT_F + t];
    out[(size_t)g * OUT_F + t] = o;
  }
}

// ============================== launch ======================================
extern "C" void kernel_launch(void* const* d_in, const int* in_sizes, int n_in,
                              void* d_out, int out_size, void* d_ws, size_t ws_size,
                              hipStream_t stream) {
  const float* x     = (const float*)d_in[0];
  const int*   ei    = (const int*)d_in[1];
  const int*   batch = (const int*)d_in[2];
  const float* Wrel  = (const float*)d_in[3];
  const float* brel  = (const float*)d_in[4];
  const float* Wroot = (const float*)d_in[5];
  const float* W1    = (const float*)d_in[6];
  const float* b1    = (const float*)d_in[7];
  const float* W2    = (const float*)d_in[8];
  const float* b2    = (const float*)d_in[9];
  float* out = (float*)d_out;

  const size_t ND = (size_t)N_NODES * D;
  unsigned short* bufA = (unsigned short*)d_ws;            // N*D bf16
  unsigned short* bufB = bufA + ND;                        // N*D bf16 (agg)
  unsigned short* bufC = bufB + ND;                        // N*D bf16 (x16)
  unsigned short* wt   = bufC + ND;                        // 3*128*512 bf16
  int* rowbeg = (int*)(wt + (size_t)N_LAYERS * 128 * 512); // N
  int* rowend = rowbeg + N_NODES;                          // N
  int* esrc   = rowend + N_NODES;                          // NBUCK*CAP
  unsigned* pairs = (unsigned*)(esrc + (size_t)NBUCK * CAP);  // NBUCK*CAP
  int* cursor = (int*)(pairs + (size_t)NBUCK * CAP);       // NBUCK

  const int* esrc_in = ei;
  const int* edst_in = ei + N_EDGES;

  // ---- prep (cast + weight frags + cursor zero) then CSR build ----
  prep_all_kernel<<<NCAST + NPREPW + 2, 256, 0, stream>>>(
      x, bufC, Wrel, Wroot, wt, cursor);
  partition_kernel<<<NB3, 256, 0, stream>>>(esrc_in, edst_in, cursor, pairs);
  bucket_sort_kernel<<<NBUCK, 256, 0, stream>>>(pairs, cursor, rowbeg, rowend, esrc);

  // ---- 3 layers: standalone agg + B-amortized GEMM ----
  const size_t WL = (size_t)128 * 512;
  const int agg_blocks = (N_NODES * 16 + 255) / 256;   // 3125
  // l0
  agg_kernel<<<agg_blocks, 256, 0, stream>>>(bufC, rowbeg, rowend, esrc, bufB);
  gemm_kernel<<<NGB, 512, 0, stream>>>(bufB, bufC, wt, brel, bufA);
  // l1
  agg_kernel<<<agg_blocks, 256, 0, stream>>>(bufA, rowbeg, rowend, esrc, bufB);
  gemm_kernel<<<NGB, 512, 0, stream>>>(bufB, bufA, wt + WL, brel + D, bufC);
  // l2
  agg_kernel<<<agg_blocks, 256, 0, stream>>>(bufC, rowbeg, rowend, esrc, bufB);
  gemm_kernel<<<NGB, 512, 0, stream>>>(bufB, bufC, wt + 2 * WL, brel + 2 * D, bufA);

  pool_head_kernel<<<N_GRAPHS, 256, 0, stream>>>(bufA, batch, W1, b1, W2, b2, out);
}

// Round 8
// 274.122 us; speedup vs baseline: 1.1767x; 1.0116x over previous
//
#include <hip/hip_runtime.h>

#define N_NODES 50000
#define N_EDGES 800000
#define D 128
#define N_LAYERS 3
#define OUT_F 16
#define N_GRAPHS 128
#define NBUCK 391            // ceil(50000/128) buckets of 128 nodes
#define EPB 4096             // edges per partition block
#define NB3 ((N_EDGES + EPB - 1) / EPB)  // 196
#define CAP 4096             // padded bucket capacity (mean 2048, sigma ~45)
#define NT32 ((N_NODES + 31) / 32)       // 1563 row-tiles of 32
#define NGB4 ((NT32 + 3) / 4)            // 391 gemm blocks (4 tiles each)
#define NCAST 6250           // cast blocks: 50000*128/4/256
#define NPREPW 96            // prep_w blocks: 24576/256

typedef __attribute__((ext_vector_type(8))) short short8;
typedef __attribute__((ext_vector_type(16))) float floatx16;

__device__ __forceinline__ unsigned short f2bf(float f) {
  unsigned int u = __float_as_uint(f);
  u += 0x7fff + ((u >> 16) & 1);   // RNE
  return (unsigned short)(u >> 16);
}
__device__ __forceinline__ float bf2f(unsigned short b) {
  return __uint_as_float(((unsigned int)b) << 16);
}
__device__ __forceinline__ float blo(unsigned v) { return __uint_as_float(v << 16); }
__device__ __forceinline__ float bhi(unsigned v) { return __uint_as_float(v & 0xffff0000u); }

// ========== CSR build: padded-bucket counting sort (2 kernels) ==============
__global__ __launch_bounds__(256) void partition_kernel(
    const int* __restrict__ src, const int* __restrict__ dst,
    int* __restrict__ cursor, unsigned* __restrict__ pairs) {
  __shared__ unsigned pk[EPB];
  __shared__ int hist[NBUCK];
  __shared__ int wcur[NBUCK];
  const int e0 = blockIdx.x * EPB;
  const int n = min(EPB, N_EDGES - e0);
  const int t = threadIdx.x;
  for (int i = t; i < NBUCK; i += 256) hist[i] = 0;
  __syncthreads();
  for (int i = t; i < n; i += 256) {
    int d = dst[e0 + i], s = src[e0 + i];
    pk[i] = ((unsigned)d << 16) | (unsigned)s;
    atomicAdd(&hist[d >> 7], 1);
  }
  __syncthreads();
  for (int i = t; i < NBUCK; i += 256)
    wcur[i] = i * CAP + (hist[i] ? atomicAdd(&cursor[i], hist[i]) : 0);
  __syncthreads();
  for (int i = t; i < n; i += 256) {
    unsigned p = pk[i];
    int pos = atomicAdd(&wcur[p >> 23], 1);
    pairs[pos] = p;
  }
}

__global__ __launch_bounds__(256) void bucket_sort_kernel(
    const unsigned* __restrict__ pairs, const int* __restrict__ cursor,
    int* __restrict__ rowbeg, int* __restrict__ rowend, int* __restrict__ esrc) {
  __shared__ unsigned pk[CAP];
  __shared__ int sorted[CAP];
  __shared__ int hist[128], off[128], cur[128];
  const int bkt = blockIdx.x;
  const int t = threadIdx.x;
  const int beg = bkt * CAP;
  const int cnt = cursor[bkt];
  if (t < 128) hist[t] = 0;
  __syncthreads();
  for (int i = t; i < cnt; i += 256) {
    unsigned p = pairs[beg + i];
    pk[i] = p;
    atomicAdd(&hist[(p >> 16) & 127], 1);
  }
  __syncthreads();
  if (t < 128) off[t] = hist[t];
  __syncthreads();
  for (int o = 1; o < 128; o <<= 1) {
    int x = (t < 128 && t >= o) ? off[t - o] : 0;
    __syncthreads();
    if (t < 128) off[t] += x;
    __syncthreads();
  }
  if (t < 128) {
    int node = bkt * 128 + t;
    if (node < N_NODES) {
      rowbeg[node] = beg + off[t] - hist[t];
      rowend[node] = beg + off[t];
    }
    cur[t] = off[t] - hist[t];
  }
  __syncthreads();
  for (int i = t; i < cnt; i += 256) {
    unsigned p = pk[i];
    int pos = atomicAdd(&cur[(p >> 16) & 127], 1);
    sorted[pos] = (int)(p & 0xFFFFu);
  }
  __syncthreads();
  for (int i = t; i < cnt; i += 256) esrc[beg + i] = sorted[i];
}

// ====== prep_all: cast x -> bf16, weights -> MFMA frags, zero cursor ========
// wt layout: [l][p:4][kst:32][lane:64][j:8] bf16 (p = phase = 32-col group).
// Element (lane,j) = B[kx][n], n = p*32+(lane&31), kx = kst*16+(lane>>5)*8+j;
// kx = seg*128+k, segs {rel_hi,rel_lo,root_hi,root_lo}.
__global__ __launch_bounds__(256) void prep_all_kernel(
    const float* __restrict__ x, unsigned short* __restrict__ x16,
    const float* __restrict__ Wrel, const float* __restrict__ Wroot,
    unsigned short* __restrict__ wt, int* __restrict__ cursor) {
  const int bid = blockIdx.x;
  const int t = threadIdx.x;
  if (bid < NCAST) {                       // ---- cast x (4 floats/thread) ----
    const int i = bid * 256 + t;
    const float4 v = *(const float4*)&x[(size_t)i * 4];
    uint2 o;
    o.x = f2bf(v.x) | ((unsigned)f2bf(v.y) << 16);
    o.y = f2bf(v.z) | ((unsigned)f2bf(v.w) << 16);
    *(uint2*)&x16[(size_t)i * 4] = o;
  } else if (bid < NCAST + NPREPW) {       // ---- weight fragments ----
    const int idx = (bid - NCAST) * 256 + t;
    const int lane = idx & 63;
    const int kst = (idx >> 6) & 31;
    const int nt = (idx >> 11) & 1;
    const int half = (idx >> 12) & 1;
    const int l = idx >> 13;
    const int n = half * 64 + nt * 32 + (lane & 31);
    const int kx0 = kst * 16 + (lane >> 5) * 8;
    const int seg = kx0 >> 7;              // same seg for all 8 j
    const int k0 = kx0 & 127;
    const int mat = seg >> 1, lo = seg & 1;
    const float* W = (mat ? Wroot : Wrel) + (size_t)l * D * D;
    unsigned short v[8];
#pragma unroll
    for (int j = 0; j < 8; ++j) {
      float w = W[(size_t)(k0 + j) * D + n];
      unsigned short hi = f2bf(w);
      v[j] = lo ? f2bf(w - bf2f(hi)) : hi;
    }
    unsigned short* dstp =
        wt + ((size_t)l * 128 + (half * 2 + nt) * 32 + kst) * 512 + lane * 8;
    *(uint4*)dstp = *(const uint4*)v;
  } else {                                 // ---- zero cursor ----
    const int i = (bid - NCAST - NPREPW) * 256 + t;
    if (i < NBUCK) cursor[i] = 0;
  }
}

// ===== aggregate: ROUND-0 geometry (measured ~18us standalone) ==============
// 16 lanes/node (4 nodes/wave), full 256B row per edge coalesced, 4-edge
// unroll, no barriers -> waves retire independently (no convoying).
__global__ __launch_bounds__(256) void agg_kernel(
    const unsigned short* __restrict__ h,
    const int* __restrict__ rowbeg, const int* __restrict__ rowend,
    const int* __restrict__ esrc, unsigned short* __restrict__ agg) {
  const int idx = blockIdx.x * 256 + threadIdx.x;
  const int n = idx >> 4;
  const int lane = idx & 15;
  if (n >= N_NODES) return;
  const int beg = rowbeg[n], end = rowend[n];
  float a0 = 0, a1 = 0, a2 = 0, a3 = 0, a4 = 0, a5 = 0, a6 = 0, a7 = 0;
  int e = beg;
  for (; e + 4 <= end; e += 4) {
    const int s0 = esrc[e],     s1 = esrc[e + 1];
    const int s2 = esrc[e + 2], s3 = esrc[e + 3];
    const uint4 v0 = *(const uint4*)&h[(size_t)s0 * D + lane * 8];
    const uint4 v1 = *(const uint4*)&h[(size_t)s1 * D + lane * 8];
    const uint4 v2 = *(const uint4*)&h[(size_t)s2 * D + lane * 8];
    const uint4 v3 = *(const uint4*)&h[(size_t)s3 * D + lane * 8];
    a0 += blo(v0.x) + blo(v1.x) + blo(v2.x) + blo(v3.x);
    a1 += bhi(v0.x) + bhi(v1.x) + bhi(v2.x) + bhi(v3.x);
    a2 += blo(v0.y) + blo(v1.y) + blo(v2.y) + blo(v3.y);
    a3 += bhi(v0.y) + bhi(v1.y) + bhi(v2.y) + bhi(v3.y);
    a4 += blo(v0.z) + blo(v1.z) + blo(v2.z) + blo(v3.z);
    a5 += bhi(v0.z) + bhi(v1.z) + bhi(v2.z) + bhi(v3.z);
    a6 += blo(v0.w) + blo(v1.w) + blo(v2.w) + blo(v3.w);
    a7 += bhi(v0.w) + bhi(v1.w) + bhi(v2.w) + bhi(v3.w);
  }
  for (; e < end; ++e) {
    const int s0 = esrc[e];
    const uint4 v0 = *(const uint4*)&h[(size_t)s0 * D + lane * 8];
    a0 += blo(v0.x); a1 += bhi(v0.x);
    a2 += blo(v0.y); a3 += bhi(v0.y);
    a4 += blo(v0.z); a5 += bhi(v0.z);
    a6 += blo(v0.w); a7 += bhi(v0.w);
  }
  uint4 o;
  o.x = f2bf(a0) | ((unsigned)f2bf(a1) << 16);
  o.y = f2bf(a2) | ((unsigned)f2bf(a3) << 16);
  o.z = f2bf(a4) | ((unsigned)f2bf(a5) << 16);
  o.w = f2bf(a6) | ((unsigned)f2bf(a7) << 16);
  *(uint4*)&agg[(size_t)n * D + lane * 8] = o;
}

// ========== GEMM v8: minimal serialization ==================================
// 256 thr / 4 waves; wave = tile (4 tiles/block); grid 391 (~1.5 blocks/CU,
// 2 resident). A/h frags: DIRECT global->reg (no LDS, no barriers, L2-hot).
// B: two 64KB halves staged to LDS per block (one barrier each), shared by
// all 4 waves -> 50MB B traffic. All per-thread loads (32 A + 16 B uint4)
// issue before the single sync -> one latency exposure per half.
__global__ __launch_bounds__(256, 2) void gemm_kernel(
    const unsigned short* __restrict__ agg, const unsigned short* __restrict__ hv,
    const unsigned short* __restrict__ wt,  // this layer's 128KB frag block
    const float* __restrict__ brel,
    unsigned short* __restrict__ outp) {
  __shared__ unsigned short blds[32768];        // 64 KB: current B half
  const int t = threadIdx.x;
  const int wave = t >> 6, lane = t & 63;
  const int r2 = lane & 31, hseg = lane >> 5;
  const int tile = blockIdx.x * 4 + wave;
  const int r0 = tile * 32;
  int arow = r0 + r2;
  if (arow >= N_NODES) arow = N_NODES - 1;

  // ---- A/h fragments straight to registers (independent, no barriers) ----
  short8 ag[8], hh[8];
  const unsigned short* ap = agg + (size_t)arow * D + hseg * 8;
  const unsigned short* hp = hv + (size_t)arow * D + hseg * 8;
#pragma unroll
  for (int i = 0; i < 8; ++i) {
    ag[i] = *(const short8*)(ap + i * 16);
    hh[i] = *(const short8*)(hp + i * 16);
  }

  // ---- 2 B-halves x 2 phases ----
#pragma unroll
  for (int pp = 0; pp < 2; ++pp) {
    if (pp) __syncthreads();                    // prev-half reads done
    const unsigned short* ws = wt + (size_t)pp * 32768;
#pragma unroll
    for (int j = 0; j < 16; ++j) {
      const int idx = t + j * 256;              // 4096 uint4 units = 64KB
      *(uint4*)&blds[idx * 8] = *(const uint4*)&ws[idx * 8];
    }
    __syncthreads();
#pragma unroll
    for (int p2 = 0; p2 < 2; ++p2) {
      floatx16 acc = {0.f};
#pragma unroll
      for (int kst = 0; kst < 32; ++kst) {
        const short8 af = (kst < 16) ? ag[kst & 7] : hh[kst & 7];
        const short8 b = *(const short8*)&blds[(p2 * 32 + kst) * 512 + lane * 8];
        acc = __builtin_amdgcn_mfma_f32_32x32x16_bf16(af, b, acc, 0, 0, 0);
      }
      const int cb = (pp * 2 + p2) * 32 + r2;
      const float bias = brel[cb];
#pragma unroll
      for (int reg = 0; reg < 16; ++reg) {
        const int orow = r0 + (reg & 3) + 8 * (reg >> 2) + 4 * hseg;
        if (orow < N_NODES)
          outp[(size_t)orow * D + cb] = f2bf(fmaxf(acc[reg] + bias, 0.f));
      }
    }
  }
}

// ============= pool (segment ranges; batch sorted) + MLP head ===============
__device__ __forceinline__ int lb_search(const int* __restrict__ a, int n, int key) {
  int lo = 0, hi = n;
  while (lo < hi) {
    int m = (lo + hi) >> 1;
    if (a[m] < key) lo = m + 1; else hi = m;
  }
  return lo;
}

__global__ __launch_bounds__(256) void pool_head_kernel(
    const unsigned short* __restrict__ h, const int* __restrict__ batch,
    const float* __restrict__ W1, const float* __restrict__ b1,
    const float* __restrict__ W2, const float* __restrict__ b2,
    float* __restrict__ out) {
  __shared__ float sums_lds[16][128];
  __shared__ float pooled[128];
  __shared__ float hidden[128];
  __shared__ int range[2];
  const int g = blockIdx.x;
  const int t = threadIdx.x;
  if (t < 2) range[t] = lb_search(batch, N_NODES, g + t);
  __syncthreads();
  const int lo = range[0], hi = range[1];
  const int rg = t >> 4, cg = t & 15;
  float a0 = 0, a1 = 0, a2 = 0, a3 = 0, a4 = 0, a5 = 0, a6 = 0, a7 = 0;
  for (int n = lo + rg; n < hi; n += 16) {
    const uint4 v = *(const uint4*)&h[(size_t)n * D + cg * 8];
    a0 += blo(v.x); a1 += bhi(v.x);
    a2 += blo(v.y); a3 += bhi(v.y);
    a4 += blo(v.z); a5 += bhi(v.z);
    a6 += blo(v.w); a7 += bhi(v.w);
  }
  sums_lds[rg][cg * 8 + 0] = a0; sums_lds[rg][cg * 8 + 1] = a1;
  sums_lds[rg][cg * 8 + 2] = a2; sums_lds[rg][cg * 8 + 3] = a3;
  sums_lds[rg][cg * 8 + 4] = a4; sums_lds[rg][cg * 8 + 5] = a5;
  sums_lds[rg][cg * 8 + 6] = a6; sums_lds[rg][cg * 8 + 7] = a7;
  __syncthreads();
  if (t < 128) {
    float s = 0.f;
#pragma unroll
    for (int r = 0; r < 16; ++r) s += sums_lds[r][t];
    pooled[t] = s / fmaxf((float)(hi - lo), 1.f);
  }
  __syncthreads();
  if (t < 128) {
    float a = b1[t];
    for (int k = 0; k < D; ++k) a += pooled[k] * W1[k * D + t];
    hidden[t] = a;
  }
  __syncthreads();
  if (t < OUT_F) {
    float o = b2[t];
    for (int k = 0; k < D; ++k) o += hidden[k] * W2[k * OUT_F + t];
    out[(size_t)g * OUT_F + t] = o;
  }
}

// ============================== launch ======================================
extern "C" void kernel_launch(void* const* d_in, const int* in_sizes, int n_in,
                              void* d_out, int out_size, void* d_ws, size_t ws_size,
                              hipStream_t stream) {
  const float* x     = (const float*)d_in[0];
  const int*   ei    = (const int*)d_in[1];
  const int*   batch = (const int*)d_in[2];
  const float* Wrel  = (const float*)d_in[3];
  const float* brel  = (const float*)d_in[4];
  const float* Wroot = (const float*)d_in[5];
  const float* W1    = (const float*)d_in[6];
  const float* b1    = (const float*)d_in[7];
  const float* W2    = (const float*)d_in[8];
  const float* b2    = (const float*)d_in[9];
  float* out = (float*)d_out;

  const size_t ND = (size_t)N_NODES * D;
  unsigned short* bufA = (unsigned short*)d_ws;            // N*D bf16
  unsigned short* bufB = bufA + ND;                        // N*D bf16 (agg)
  unsigned short* bufC = bufB + ND;                        // N*D bf16 (x16)
  unsigned short* wt   = bufC + ND;                        // 3*128*512 bf16
  int* rowbeg = (int*)(wt + (size_t)N_LAYERS * 128 * 512); // N
  int* rowend = rowbeg + N_NODES;                          // N
  int* esrc   = rowend + N_NODES;                          // NBUCK*CAP
  unsigned* pairs = (unsigned*)(esrc + (size_t)NBUCK * CAP);  // NBUCK*CAP
  int* cursor = (int*)(pairs + (size_t)NBUCK * CAP);       // NBUCK

  const int* esrc_in = ei;
  const int* edst_in = ei + N_EDGES;

  // ---- prep (cast + weight frags + cursor zero) then CSR build ----
  prep_all_kernel<<<NCAST + NPREPW + 2, 256, 0, stream>>>(
      x, bufC, Wrel, Wroot, wt, cursor);
  partition_kernel<<<NB3, 256, 0, stream>>>(esrc_in, edst_in, cursor, pairs);
  bucket_sort_kernel<<<NBUCK, 256, 0, stream>>>(pairs, cursor, rowbeg, rowend, esrc);

  // ---- 3 layers: standalone agg + low-latency GEMM ----
  const size_t WL = (size_t)128 * 512;
  const int agg_blocks = (N_NODES * 16 + 255) / 256;   // 3125
  // l0
  agg_kernel<<<agg_blocks, 256, 0, stream>>>(bufC, rowbeg, rowend, esrc, bufB);
  gemm_kernel<<<NGB4, 256, 0, stream>>>(bufB, bufC, wt, brel, bufA);
  // l1
  agg_kernel<<<agg_blocks, 256, 0, stream>>>(bufA, rowbeg, rowend, esrc, bufB);
  gemm_kernel<<<NGB4, 256, 0, stream>>>(bufB, bufA, wt + WL, brel + D, bufC);
  // l2
  agg_kernel<<<agg_blocks, 256, 0, stream>>>(bufC, rowbeg, rowend, esrc, bufB);
  gemm_kernel<<<NGB4, 256, 0, stream>>>(bufB, bufC, wt + 2 * WL, brel + 2 * D, bufA);

  pool_head_kernel<<<N_GRAPHS, 256, 0, stream>>>(bufA, batch, W1, b1, W2, b2, out);
}